// Round 2
// baseline (222.873 us; speedup 1.0000x reference)
//
#include <hip/hip_runtime.h>

#define NQKV_ 384
#define MAGIC_ 0x5CA1AB1E

typedef __bf16 bf;
typedef __attribute__((ext_vector_type(4))) __bf16 bf16x4;
typedef __attribute__((ext_vector_type(8))) __bf16 bf16x8;
typedef __attribute__((ext_vector_type(4))) float f32x4;

__device__ __forceinline__ float fast_exp2(float x) {
#if __has_builtin(__builtin_amdgcn_exp2f)
  return __builtin_amdgcn_exp2f(x);
#else
  return exp2f(x);
#endif
}
__device__ __forceinline__ float fast_rcp(float x) {
#if __has_builtin(__builtin_amdgcn_rcpf)
  return __builtin_amdgcn_rcpf(x);
#else
  return 1.0f / x;
#endif
}

// Swizzle qkv_w / full_w (fp32 [L][K][N]) into bf16 MFMA B-fragment order via
// LDS-staged transpose: coalesced float4 source loads -> 128x16 LDS tile
// (pad 17: 2-way bank aliasing only, free) -> fully coalesced 16 B stores.
// Blocks 0..95: wq, (layer = blk/24, t = blk%24). Blocks 96..127: wf.
// dest element = ((layer*T + t)*4 + s)*512 + lane*8 + j
//   = blk_local*2048 + tid*8 + j,  value = W[k = s*32+(lane>>4)*8+j][t*16+(lane&15)]
__global__ __launch_bounds__(256) void k_prep_w(const float* __restrict__ qkv_w,
                                                const float* __restrict__ full_w,
                                                bf* __restrict__ wq, bf* __restrict__ wf) {
  __shared__ float tile[128][17];
  const int blk = blockIdx.x, tid = threadIdx.x;
  const float* src;
  bf* dst;
  int ldn;
  if (blk < 96) {
    int layer = blk / 24, t = blk % 24;
    src = qkv_w + (size_t)layer * 128 * NQKV_ + t * 16;
    dst = wq + ((size_t)blk << 11);
    ldn = NQKV_;
  } else {
    int b2 = blk - 96;
    src = full_w + (size_t)(b2 >> 3) * 128 * 128 + (b2 & 7) * 16;
    dst = wf + ((size_t)b2 << 11);
    ldn = 128;
  }
#pragma unroll
  for (int pass = 0; pass < 2; ++pass) {
    int k = (tid >> 2) + pass * 64;
    int c4 = (tid & 3) * 4;
    float4 f = *(const float4*)(src + (size_t)k * ldn + c4);
    tile[k][c4 + 0] = f.x; tile[k][c4 + 1] = f.y;
    tile[k][c4 + 2] = f.z; tile[k][c4 + 3] = f.w;
  }
  __syncthreads();
  int s = tid >> 6, lane = tid & 63;
  int k0 = s * 32 + ((lane >> 4) << 3), n16 = lane & 15;
  bf16x8 v;
#pragma unroll
  for (int j = 0; j < 8; ++j) v[j] = (bf)tile[k0 + j][n16];
  *(bf16x8*)(dst + tid * 8) = v;   // 16 B/thread, wave-contiguous
}

// One block per (sequence b, channel-half). 256 blocks x 1024 threads (16 waves).
// 128 KB LDS -> 1 block/CU, 16 waves/CU.
// Partner pairing: b = bidx&127, half = bidx>>7 -> peer = bidx^128 on the SAME
// XCD under round-robin dispatch, so flag+att exchange stays in per-XCD L2.
__global__ __launch_bounds__(1024, 4) void k_net(
    const float* __restrict__ x, const float* __restrict__ in_w,
    const float* __restrict__ in_b, const float* __restrict__ ln_g,
    const float* __restrict__ ln_b, const float* __restrict__ qkv_b,
    const float* __restrict__ full_b, const float* __restrict__ out_w,
    const float* __restrict__ out_b, const bf* __restrict__ wq,
    const bf* __restrict__ wf, bf* __restrict__ attg,
    int* __restrict__ flags, float* __restrict__ out) {
  __shared__ float h_s[81 * 128];        // 41472 B  residual stream (fp32, persistent)
  __shared__ bf afrag[96 * 128];         // 24576 B  A-fragments (LN out / att), bf16
  __shared__ float q_s[81 * 64];         // 20736 B  q*log2e for this half
  __shared__ float kvf[81 * 64 * 2];     // 41472 B  interleaved (k,v) fp32
                                         // total: 128256 B

  const int tid = threadIdx.x;
  const int bidx = blockIdx.x;
  const int b = bidx & 127, half = bidx >> 7, c0 = half * 64;
  const int wave = tid >> 6, lane = tid & 63, l15 = lane & 15, quad = lane >> 4;
  const float log2e = 1.4426950408889634f;

  // ---- h = x @ in_w + in_b ----
  {
    const float* xb = x + (size_t)b * 162;
    for (int i = tid; i < 81 * 128; i += 1024) {
      int p = i >> 7, cc = i & 127;
      h_s[i] = xb[p * 2] * in_w[cc] + xb[p * 2 + 1] * in_w[128 + cc] + in_b[cc];
    }
  }
  __syncthreads();

  for (int layer = 0; layer < 4; ++layer) {
    const bf* wqL = wq + (size_t)layer * 24 * 2048;
    const bf* wfL = wf + (size_t)layer * 8 * 2048;

    // B-fragment address for qkv tile tau (tau = wave + 16*i)
    auto qkv_baddr = [&](int tau) {
      int Nt = tau % 12;
      int sec = Nt >> 2, off = Nt & 3;
      int tg = sec * 8 + half * 4 + off;
      return wqL + ((size_t)tg * 4) * 512 + lane * 8;
    };

    // Prefetch tile-0 B fragments for the qkv GEMM; latency hides under LN.
    bf16x8 b0, b1, b2, b3;
    {
      const bf* p = qkv_baddr(wave);
      b0 = *(const bf16x8*)(p);
      b1 = *(const bf16x8*)(p + 512);
      b2 = *(const bf16x8*)(p + 1024);
      b3 = *(const bf16x8*)(p + 1536);
    }

    // ---- LayerNorm rows -> bf16 A-fragments (single pass) ----
    {
      const float* lg = ln_g + layer * 128;
      const float* lb = ln_b + layer * 128;
      int row = tid >> 3, g8 = tid & 7;
      if (row < 81) {
        const float* hr = h_s + row * 128;
        float vals[16];
        float sum = 0.f, ssq = 0.f;
#pragma unroll
        for (int it = 0; it < 4; ++it) {
          float4 f = *(const float4*)(hr + g8 * 4 + it * 32);
          vals[it * 4 + 0] = f.x; vals[it * 4 + 1] = f.y;
          vals[it * 4 + 2] = f.z; vals[it * 4 + 3] = f.w;
          sum += f.x + f.y + f.z + f.w;
          ssq += f.x * f.x + f.y * f.y + f.z * f.z + f.w * f.w;
        }
#pragma unroll
        for (int off = 1; off < 8; off <<= 1) {
          sum += __shfl_xor(sum, off);
          ssq += __shfl_xor(ssq, off);
        }
        float mu = sum * (1.f / 128.f);
        float rs = rsqrtf(ssq * (1.f / 128.f) - mu * mu + 1e-5f);
        int mt = row >> 4, m = row & 15;
        int lgp = g8 >> 1, j0 = (g8 & 1) * 4;
#pragma unroll
        for (int it = 0; it < 4; ++it) {
          int cc = g8 * 4 + it * 32;
          float4 gg = *(const float4*)(lg + cc);
          float4 bb = *(const float4*)(lb + cc);
          bf16x4 nv;
          nv[0] = (bf)((vals[it * 4 + 0] - mu) * rs * gg.x + bb.x);
          nv[1] = (bf)((vals[it * 4 + 1] - mu) * rs * gg.y + bb.y);
          nv[2] = (bf)((vals[it * 4 + 2] - mu) * rs * gg.z + bb.z);
          nv[3] = (bf)((vals[it * 4 + 3] - mu) * rs * gg.w + bb.w);
          *(bf16x4*)(afrag + (((mt * 4 + it) * 64 + (lgp * 16 + m)) << 3) + j0) = nv;
        }
      }
    }
    __syncthreads();

    // ---- qkv GEMM (half): [96x128] @ [128x192], 72 tiles / 16 waves,
    //      register double-buffered B fragments ----
    {
      f32x4 acc[5] = {};
#pragma unroll
      for (int i = 0; i < 5; ++i) {
        int tau = wave + 16 * i;
        bf16x8 n0, n1, n2, n3;
        if (i < 4) {
          int tnx = wave + 16 * (i + 1);
          if (tnx >= 72) tnx = tau;          // clamp: redundant in-bounds load
          const bf* p = qkv_baddr(tnx);
          n0 = *(const bf16x8*)(p);
          n1 = *(const bf16x8*)(p + 512);
          n2 = *(const bf16x8*)(p + 1024);
          n3 = *(const bf16x8*)(p + 1536);
        }
        if (tau < 72) {
          int Mt = tau / 12;
          bf16x8 a;
          a = *(const bf16x8*)(afrag + (((Mt * 4 + 0) * 64 + lane) << 3));
          acc[i] = __builtin_amdgcn_mfma_f32_16x16x32_bf16(a, b0, acc[i], 0, 0, 0);
          a = *(const bf16x8*)(afrag + (((Mt * 4 + 1) * 64 + lane) << 3));
          acc[i] = __builtin_amdgcn_mfma_f32_16x16x32_bf16(a, b1, acc[i], 0, 0, 0);
          a = *(const bf16x8*)(afrag + (((Mt * 4 + 2) * 64 + lane) << 3));
          acc[i] = __builtin_amdgcn_mfma_f32_16x16x32_bf16(a, b2, acc[i], 0, 0, 0);
          a = *(const bf16x8*)(afrag + (((Mt * 4 + 3) * 64 + lane) << 3));
          acc[i] = __builtin_amdgcn_mfma_f32_16x16x32_bf16(a, b3, acc[i], 0, 0, 0);
        }
        if (i < 4) { b0 = n0; b1 = n1; b2 = n2; b3 = n3; }
      }
      const float* qb = qkv_b + layer * NQKV_;
#pragma unroll
      for (int i = 0; i < 5; ++i) {
        int tau = wave + 16 * i;
        if (tau < 72) {
          int Mt = tau / 12, Nt = tau % 12;
          int sec = Nt >> 2, off = Nt & 3;
          int cl = off * 16 + l15;           // 0..63 within half-section
          float bias = qb[sec * 128 + c0 + cl];
          int Rb = Mt * 16 + quad * 4;
#pragma unroll
          for (int r = 0; r < 4; ++r) {
            int R = Rb + r;
            if (R < 81) {
              float vv = acc[i][r] + bias;
              if (sec == 0)      q_s[R * 64 + cl] = vv * log2e;
              else if (sec == 1) kvf[(R * 64 + cl) * 2] = vv;
              else               kvf[(R * 64 + cl) * 2 + 1] = vv;
            }
          }
        }
      }
    }
    __syncthreads();

    // ---- per-channel attention: stream k once, 5-6 query accumulators ----
    // No max-shift: exp2 args are bounded (LN-constrained activations), softmax
    // ratio is relative-precision-identical.
    {
      int c = tid & 63, qs = wave;
      int cc = c0 + c;
      int sc = cc >> 5, qc = (cc >> 3) & 3, jc = cc & 7;
      bf* ag = attg + ((size_t)(b * 2 + half) * 81) * 64;

      float xq[6], Na[6], Da[6];
#pragma unroll
      for (int j = 0; j < 5; ++j) {
        xq[j] = q_s[(qs + 16 * j) * 64 + c];
        Na[j] = 0.f; Da[j] = 0.f;
      }
      xq[5] = 0.f; Na[5] = 0.f; Da[5] = 0.f;
      if (qs == 0) {                 // wave-uniform branch: wave 0 carries q=80
        xq[5] = q_s[80 * 64 + c];
#pragma unroll 3
        for (int kk = 0; kk < 81; ++kk) {
          float2 A = *(const float2*)(kvf + (kk * 64 + c) * 2);
#pragma unroll
          for (int j = 0; j < 6; ++j) {
            float e = fast_exp2(xq[j] * A.x);
            Da[j] += e; Na[j] = __builtin_fmaf(e, A.y, Na[j]);
          }
        }
      } else {
#pragma unroll 3
        for (int kk = 0; kk < 81; ++kk) {
          float2 A = *(const float2*)(kvf + (kk * 64 + c) * 2);
#pragma unroll
          for (int j = 0; j < 5; ++j) {
            float e = fast_exp2(xq[j] * A.x);
            Da[j] += e; Na[j] = __builtin_fmaf(e, A.y, Na[j]);
          }
        }
      }
#pragma unroll
      for (int j = 0; j < 6; ++j) {
        if (j == 5 && qs != 0) break;
        int qq = qs + 16 * j;        // j==5 only on wave 0 -> q=80
        bf bv = (bf)(Na[j] * fast_rcp(Da[j]));
        afrag[((((qq >> 4) * 4 + sc) * 64 + qc * 16 + (qq & 15)) << 3) + jc] = bv;
        ag[qq * 64 + c] = bv;
      }
    }
    __syncthreads();

    // ---- full GEMM: own-half K-chunks overlap the partner flag-wait;
    //      partner-half B fragments prefetched under the exchange ----
    f32x4 acc[3] = {};
    {
      int sbase = half * 2;          // own channels: s in {2*half, 2*half+1}
      bf16x8 bo[6];
#pragma unroll
      for (int i = 0; i < 3; ++i) {
        int tau = wave + 16 * i, Nt = tau & 7;
        bo[i * 2 + 0] = *(const bf16x8*)(wfL + ((Nt * 4 + sbase + 0) * 512 + lane * 8));
        bo[i * 2 + 1] = *(const bf16x8*)(wfL + ((Nt * 4 + sbase + 1) * 512 + lane * 8));
      }
      if (tid == 0) {
        __hip_atomic_store(&flags[bidx * 4 + layer], MAGIC_, __ATOMIC_RELEASE,
                           __HIP_MEMORY_SCOPE_AGENT);
      }
#pragma unroll
      for (int i = 0; i < 3; ++i) {
        int tau = wave + 16 * i, Mt = tau >> 3;
        bf16x8 a;
        a = *(const bf16x8*)(afrag + (((Mt * 4 + sbase + 0) * 64 + lane) << 3));
        acc[i] = __builtin_amdgcn_mfma_f32_16x16x32_bf16(a, bo[i * 2 + 0], acc[i], 0, 0, 0);
        a = *(const bf16x8*)(afrag + (((Mt * 4 + sbase + 1) * 64 + lane) << 3));
        acc[i] = __builtin_amdgcn_mfma_f32_16x16x32_bf16(a, bo[i * 2 + 1], acc[i], 0, 0, 0);
      }
    }
    // partner-half B prefetch: issue before the spin so L2 latency hides there
    bf16x8 bp[6];
    {
      int pbase = 2 - half * 2;
#pragma unroll
      for (int i = 0; i < 3; ++i) {
        int tau = wave + 16 * i, Nt = tau & 7;
        bp[i * 2 + 0] = *(const bf16x8*)(wfL + ((Nt * 4 + pbase + 0) * 512 + lane * 8));
        bp[i * 2 + 1] = *(const bf16x8*)(wfL + ((Nt * 4 + pbase + 1) * 512 + lane * 8));
      }
    }
    if (tid == 0) {
      int peer = (bidx ^ 128) * 4 + layer;
      long guard = 0;
      while (__hip_atomic_load(&flags[peer], __ATOMIC_ACQUIRE,
                               __HIP_MEMORY_SCOPE_AGENT) != MAGIC_) {
        __builtin_amdgcn_s_sleep(2);
        if (++guard > (1L << 27)) break;   // safety valve vs. hang
      }
    }
    __syncthreads();
    {
      const bf* src = attg + ((size_t)(b * 2 + (1 - half)) * 81) * 64;
      int pc0 = 64 - c0;
      for (int i = tid; i < 81 * 32; i += 1024) {
        int qq = i >> 5, cp = (i & 31) * 2;
        int ccp = pc0 + cp;                       // (ccp&7) is even
        ushort2 val = *(const ushort2*)((const unsigned short*)src + qq * 64 + cp);
        int idx = ((((qq >> 4) * 4 + (ccp >> 5)) * 64 + ((ccp >> 3) & 3) * 16 + (qq & 15)) << 3) + (ccp & 7);
        *(ushort2*)((unsigned short*)afrag + idx) = val;
      }
    }
    __syncthreads();

    // ---- partner-half K-chunks + bias + relu + residual into h_s ----
    {
      int pbase = 2 - half * 2;
#pragma unroll
      for (int i = 0; i < 3; ++i) {
        int tau = wave + 16 * i, Mt = tau >> 3;
        bf16x8 a;
        a = *(const bf16x8*)(afrag + (((Mt * 4 + pbase + 0) * 64 + lane) << 3));
        acc[i] = __builtin_amdgcn_mfma_f32_16x16x32_bf16(a, bp[i * 2 + 0], acc[i], 0, 0, 0);
        a = *(const bf16x8*)(afrag + (((Mt * 4 + pbase + 1) * 64 + lane) << 3));
        acc[i] = __builtin_amdgcn_mfma_f32_16x16x32_bf16(a, bp[i * 2 + 1], acc[i], 0, 0, 0);
      }
      const float* fb = full_b + layer * 128;
#pragma unroll
      for (int i = 0; i < 3; ++i) {
        int tau = wave + 16 * i;
        int Mt = tau >> 3, Nt = tau & 7;
        int col = Nt * 16 + l15;
        float bias = fb[col];
        int Rb = Mt * 16 + quad * 4;
#pragma unroll
        for (int r = 0; r < 4; ++r) {
          int R = Rb + r;
          if (R < 81) h_s[R * 128 + col] += fmaxf(acc[i][r] + bias, 0.f);
        }
      }
    }
    __syncthreads();
  }

  // ---- out = h @ out_w + out_b (half 0 writes) ----
  if (half == 0) {
    int row = tid >> 3, g8 = tid & 7;
    if (row < 81) {
      const float* hr = h_s + row * 128;
      float o0 = 0.f, o1 = 0.f, o2 = 0.f, o3 = 0.f;
#pragma unroll
      for (int it = 0; it < 4; ++it) {
        int cc = g8 * 4 + it * 32;
        float4 f = *(const float4*)(hr + cc);
        float4 wA = *(const float4*)(out_w + (cc + 0) * 4);
        float4 wB = *(const float4*)(out_w + (cc + 1) * 4);
        float4 wC = *(const float4*)(out_w + (cc + 2) * 4);
        float4 wD = *(const float4*)(out_w + (cc + 3) * 4);
        o0 += f.x * wA.x + f.y * wB.x + f.z * wC.x + f.w * wD.x;
        o1 += f.x * wA.y + f.y * wB.y + f.z * wC.y + f.w * wD.y;
        o2 += f.x * wA.z + f.y * wB.z + f.z * wC.z + f.w * wD.z;
        o3 += f.x * wA.w + f.y * wB.w + f.z * wC.w + f.w * wD.w;
      }
#pragma unroll
      for (int off = 1; off < 8; off <<= 1) {
        o0 += __shfl_xor(o0, off); o1 += __shfl_xor(o1, off);
        o2 += __shfl_xor(o2, off); o3 += __shfl_xor(o3, off);
      }
      if (g8 == 0) {
        *(float4*)(out + ((size_t)b * 81 + row) * 4) =
            make_float4(o0 + out_b[0], o1 + out_b[1], o2 + out_b[2], o3 + out_b[3]);
      }
    }
  }
}

extern "C" void kernel_launch(void* const* d_in, const int* in_sizes, int n_in,
                              void* d_out, int out_size, void* d_ws, size_t ws_size,
                              hipStream_t stream) {
  const float* x      = (const float*)d_in[0];
  const float* in_w   = (const float*)d_in[1];
  const float* in_b   = (const float*)d_in[2];
  const float* ln_g   = (const float*)d_in[3];
  const float* ln_b   = (const float*)d_in[4];
  const float* qkv_w  = (const float*)d_in[5];
  const float* qkv_b  = (const float*)d_in[6];
  const float* full_w = (const float*)d_in[7];
  const float* full_b = (const float*)d_in[8];
  const float* out_w  = (const float*)d_in[9];
  const float* out_b  = (const float*)d_in[10];

  bf* wq     = (bf*)d_ws;                  // 196608 bf16
  bf* wf     = wq + 196608;                // 65536 bf16
  bf* attg   = wf + 65536;                 // 128*2*81*64 = 1327104 bf16
  int* flags = (int*)(attg + 1327104);     // 256*4 ints (poisoned each launch)
  float* out = (float*)d_out;

  k_prep_w<<<128, 256, 0, stream>>>(qkv_w, full_w, wq, wf);
  k_net<<<256, 1024, 0, stream>>>(x, in_w, in_b, ln_g, ln_b, qkv_b, full_b,
                                  out_w, out_b, wq, wf, attg, flags, out);
}

// Round 3
// 204.787 us; speedup vs baseline: 1.0883x; 1.0883x over previous
//
#include <hip/hip_runtime.h>

#define NQKV_ 384
#define MAGIC_ 0x5CA1AB1E

typedef __bf16 bf;
typedef __attribute__((ext_vector_type(4))) __bf16 bf16x4;
typedef __attribute__((ext_vector_type(8))) __bf16 bf16x8;
typedef __attribute__((ext_vector_type(4))) float f32x4;

__device__ __forceinline__ float fast_exp2(float x) {
#if __has_builtin(__builtin_amdgcn_exp2f)
  return __builtin_amdgcn_exp2f(x);
#else
  return exp2f(x);
#endif
}
__device__ __forceinline__ float fast_rcp(float x) {
#if __has_builtin(__builtin_amdgcn_rcpf)
  return __builtin_amdgcn_rcpf(x);
#else
  return 1.0f / x;
#endif
}

// Swizzle qkv_w / full_w (fp32 [L][K][N]) into bf16 MFMA B-fragment order via
// LDS-staged transpose: coalesced float4 source loads -> 128x16 LDS tile
// (pad 17: 2-way bank aliasing only, free) -> fully coalesced 16 B stores.
// Blocks 0..95: wq, (layer = blk/24, t = blk%24). Blocks 96..127: wf.
__global__ __launch_bounds__(256) void k_prep_w(const float* __restrict__ qkv_w,
                                                const float* __restrict__ full_w,
                                                bf* __restrict__ wq, bf* __restrict__ wf) {
  __shared__ float tile[128][17];
  const int blk = blockIdx.x, tid = threadIdx.x;
  const float* src;
  bf* dst;
  int ldn;
  if (blk < 96) {
    int layer = blk / 24, t = blk % 24;
    src = qkv_w + (size_t)layer * 128 * NQKV_ + t * 16;
    dst = wq + ((size_t)blk << 11);
    ldn = NQKV_;
  } else {
    int b2 = blk - 96;
    src = full_w + (size_t)(b2 >> 3) * 128 * 128 + (b2 & 7) * 16;
    dst = wf + ((size_t)b2 << 11);
    ldn = 128;
  }
#pragma unroll
  for (int pass = 0; pass < 2; ++pass) {
    int k = (tid >> 2) + pass * 64;
    int c4 = (tid & 3) * 4;
    float4 f = *(const float4*)(src + (size_t)k * ldn + c4);
    tile[k][c4 + 0] = f.x; tile[k][c4 + 1] = f.y;
    tile[k][c4 + 2] = f.z; tile[k][c4 + 3] = f.w;
  }
  __syncthreads();
  int s = tid >> 6, lane = tid & 63;
  int k0 = s * 32 + ((lane >> 4) << 3), n16 = lane & 15;
  bf16x8 v;
#pragma unroll
  for (int j = 0; j < 8; ++j) v[j] = (bf)tile[k0 + j][n16];
  *(bf16x8*)(dst + tid * 8) = v;   // 16 B/thread, wave-contiguous
}

// One block per (sequence b, channel-half). 256 blocks x 1024 threads (16 waves).
// 128 KB LDS -> 1 block/CU, 16 waves/CU = 4 waves/EU.
// amdgpu_waves_per_eu(4,4): compiler may use up to 128 VGPRs (LDS already caps
// occupancy at 4/EU) instead of squeezing to the 64-reg tier and spilling.
// Partner pairing: b = bidx&127, half = bidx>>7 -> peer = bidx^128 on the SAME
// XCD under round-robin dispatch, so flag+att exchange stays in per-XCD L2.
__global__ __launch_bounds__(1024)
__attribute__((amdgpu_waves_per_eu(4, 4))) void k_net(
    const float* __restrict__ x, const float* __restrict__ in_w,
    const float* __restrict__ in_b, const float* __restrict__ ln_g,
    const float* __restrict__ ln_b, const float* __restrict__ qkv_b,
    const float* __restrict__ full_b, const float* __restrict__ out_w,
    const float* __restrict__ out_b, const bf* __restrict__ wq,
    const bf* __restrict__ wf, bf* __restrict__ attg,
    int* __restrict__ flags, float* __restrict__ out) {
  __shared__ float h_s[81 * 128];        // 41472 B  residual stream (fp32, persistent)
  __shared__ bf afrag[96 * 128];         // 24576 B  A-fragments (LN out / att), bf16
  __shared__ float q_s[81 * 64];         // 20736 B  q*log2e for this half
  __shared__ float kvf[81 * 64 * 2];     // 41472 B  interleaved (k,v) fp32
                                         // total: 128256 B

  const int tid = threadIdx.x;
  const int bidx = blockIdx.x;
  const int b = bidx & 127, half = bidx >> 7, c0 = half * 64;
  const int wave = tid >> 6, lane = tid & 63, l15 = lane & 15, quad = lane >> 4;
  const float log2e = 1.4426950408889634f;

  // ---- h = x @ in_w + in_b ----
  {
    const float* xb = x + (size_t)b * 162;
    for (int i = tid; i < 81 * 128; i += 1024) {
      int p = i >> 7, cc = i & 127;
      h_s[i] = xb[p * 2] * in_w[cc] + xb[p * 2 + 1] * in_w[128 + cc] + in_b[cc];
    }
  }
  __syncthreads();

  for (int layer = 0; layer < 4; ++layer) {
    const bf* wqL = wq + (size_t)layer * 24 * 2048;
    const bf* wfL = wf + (size_t)layer * 8 * 2048;

    // ---- LayerNorm rows -> bf16 A-fragments (single pass) ----
    {
      const float* lg = ln_g + layer * 128;
      const float* lb = ln_b + layer * 128;
      int row = tid >> 3, g8 = tid & 7;
      if (row < 81) {
        const float* hr = h_s + row * 128;
        float vals[16];
        float sum = 0.f, ssq = 0.f;
#pragma unroll
        for (int it = 0; it < 4; ++it) {
          float4 f = *(const float4*)(hr + g8 * 4 + it * 32);
          vals[it * 4 + 0] = f.x; vals[it * 4 + 1] = f.y;
          vals[it * 4 + 2] = f.z; vals[it * 4 + 3] = f.w;
          sum += f.x + f.y + f.z + f.w;
          ssq += f.x * f.x + f.y * f.y + f.z * f.z + f.w * f.w;
        }
#pragma unroll
        for (int off = 1; off < 8; off <<= 1) {
          sum += __shfl_xor(sum, off);
          ssq += __shfl_xor(ssq, off);
        }
        float mu = sum * (1.f / 128.f);
        float rs = rsqrtf(ssq * (1.f / 128.f) - mu * mu + 1e-5f);
        int mt = row >> 4, m = row & 15;
        int lgp = g8 >> 1, j0 = (g8 & 1) * 4;
#pragma unroll
        for (int it = 0; it < 4; ++it) {
          int cc = g8 * 4 + it * 32;
          float4 gg = *(const float4*)(lg + cc);
          float4 bb = *(const float4*)(lb + cc);
          bf16x4 nv;
          nv[0] = (bf)((vals[it * 4 + 0] - mu) * rs * gg.x + bb.x);
          nv[1] = (bf)((vals[it * 4 + 1] - mu) * rs * gg.y + bb.y);
          nv[2] = (bf)((vals[it * 4 + 2] - mu) * rs * gg.z + bb.z);
          nv[3] = (bf)((vals[it * 4 + 3] - mu) * rs * gg.w + bb.w);
          *(bf16x4*)(afrag + (((mt * 4 + it) * 64 + (lgp * 16 + m)) << 3) + j0) = nv;
        }
      }
    }
    __syncthreads();

    // ---- qkv GEMM (half): [96x128] @ [128x192], 72 tiles / 16 waves ----
    {
      f32x4 acc[5] = {};
#pragma unroll
      for (int i = 0; i < 5; ++i) {
        int tau = wave + 16 * i;
        if (tau < 72) {
          int Mt = tau / 12, Nt = tau % 12;
          int sec = Nt >> 2, off = Nt & 3;
          int tg = sec * 8 + half * 4 + off;
#pragma unroll
          for (int s = 0; s < 4; ++s) {
            bf16x8 a = *(const bf16x8*)(afrag + (((Mt * 4 + s) * 64 + lane) << 3));
            bf16x8 bb = *(const bf16x8*)(wqL + ((tg * 4 + s) * 512 + lane * 8));
            acc[i] = __builtin_amdgcn_mfma_f32_16x16x32_bf16(a, bb, acc[i], 0, 0, 0);
          }
        }
      }
      const float* qb = qkv_b + layer * NQKV_;
#pragma unroll
      for (int i = 0; i < 5; ++i) {
        int tau = wave + 16 * i;
        if (tau < 72) {
          int Mt = tau / 12, Nt = tau % 12;
          int sec = Nt >> 2, off = Nt & 3;
          int cl = off * 16 + l15;           // 0..63 within half-section
          float bias = qb[sec * 128 + c0 + cl];
          int Rb = Mt * 16 + quad * 4;
#pragma unroll
          for (int r = 0; r < 4; ++r) {
            int R = Rb + r;
            if (R < 81) {
              float vv = acc[i][r] + bias;
              if (sec == 0)      q_s[R * 64 + cl] = vv * log2e;
              else if (sec == 1) kvf[(R * 64 + cl) * 2] = vv;
              else               kvf[(R * 64 + cl) * 2 + 1] = vv;
            }
          }
        }
      }
    }
    __syncthreads();

    // ---- per-channel attention: stream k once, 5-6 query accumulators ----
    // No max-shift: exp2 args are bounded (LN-constrained activations), softmax
    // ratio is relative-precision-identical.
    {
      int c = tid & 63, qs = wave;
      int cc = c0 + c;
      int sc = cc >> 5, qc = (cc >> 3) & 3, jc = cc & 7;
      bf* ag = attg + ((size_t)(b * 2 + half) * 81) * 64;

      float xq[6], Na[6], Da[6];
#pragma unroll
      for (int j = 0; j < 5; ++j) {
        xq[j] = q_s[(qs + 16 * j) * 64 + c];
        Na[j] = 0.f; Da[j] = 0.f;
      }
      xq[5] = 0.f; Na[5] = 0.f; Da[5] = 0.f;
      if (qs == 0) {                 // wave-uniform branch: wave 0 carries q=80
        xq[5] = q_s[80 * 64 + c];
#pragma unroll 3
        for (int kk = 0; kk < 81; ++kk) {
          float2 A = *(const float2*)(kvf + (kk * 64 + c) * 2);
#pragma unroll
          for (int j = 0; j < 6; ++j) {
            float e = fast_exp2(xq[j] * A.x);
            Da[j] += e; Na[j] = __builtin_fmaf(e, A.y, Na[j]);
          }
        }
      } else {
#pragma unroll 3
        for (int kk = 0; kk < 81; ++kk) {
          float2 A = *(const float2*)(kvf + (kk * 64 + c) * 2);
#pragma unroll
          for (int j = 0; j < 5; ++j) {
            float e = fast_exp2(xq[j] * A.x);
            Da[j] += e; Na[j] = __builtin_fmaf(e, A.y, Na[j]);
          }
        }
      }
#pragma unroll
      for (int j = 0; j < 6; ++j) {
        if (j == 5 && qs != 0) break;
        int qq = qs + 16 * j;        // j==5 only on wave 0 -> q=80
        bf bv = (bf)(Na[j] * fast_rcp(Da[j]));
        afrag[((((qq >> 4) * 4 + sc) * 64 + qc * 16 + (qq & 15)) << 3) + jc] = bv;
        ag[qq * 64 + c] = bv;
      }
    }
    __syncthreads();

    // ---- publish own att half; own-half full-GEMM K-chunks overlap the wait ----
    if (tid == 0) {
      __hip_atomic_store(&flags[bidx * 4 + layer], MAGIC_, __ATOMIC_RELEASE,
                         __HIP_MEMORY_SCOPE_AGENT);
    }
    f32x4 acc[3] = {};
    {
      int sbase = half * 2;          // own channels: s in {2*half, 2*half+1}
#pragma unroll
      for (int i = 0; i < 3; ++i) {
        int tau = wave + 16 * i;
        int Mt = tau >> 3, Nt = tau & 7;
#pragma unroll
        for (int ss = 0; ss < 2; ++ss) {
          int s = sbase + ss;
          bf16x8 a = *(const bf16x8*)(afrag + (((Mt * 4 + s) * 64 + lane) << 3));
          bf16x8 bb = *(const bf16x8*)(wfL + ((Nt * 4 + s) * 512 + lane * 8));
          acc[i] = __builtin_amdgcn_mfma_f32_16x16x32_bf16(a, bb, acc[i], 0, 0, 0);
        }
      }
    }
    // Relaxed spin (no per-iteration L2 invalidate), single acquire fence after.
    if (tid == 0) {
      int peer = (bidx ^ 128) * 4 + layer;
      long guard = 0;
      while (__hip_atomic_load(&flags[peer], __ATOMIC_RELAXED,
                               __HIP_MEMORY_SCOPE_AGENT) != MAGIC_) {
        __builtin_amdgcn_s_sleep(2);
        if (++guard > (1L << 27)) break;   // safety valve vs. hang
      }
      __builtin_amdgcn_fence(__ATOMIC_ACQUIRE, "agent");
    }
    __syncthreads();
    {
      const bf* src = attg + ((size_t)(b * 2 + (1 - half)) * 81) * 64;
      int pc0 = 64 - c0;
      for (int i = tid; i < 81 * 16; i += 1024) {
        int qq = i >> 4, cp = (i & 15) * 4;
        int ccp = pc0 + cp;                       // (ccp&7) in {0,4}
        ushort4 val = *(const ushort4*)((const unsigned short*)src + qq * 64 + cp);
        int idx = ((((qq >> 4) * 4 + (ccp >> 5)) * 64 + ((ccp >> 3) & 3) * 16 + (qq & 15)) << 3) + (ccp & 7);
        *(ushort4*)((unsigned short*)afrag + idx) = val;
      }
    }
    __syncthreads();

    // ---- partner-half K-chunks + bias + relu + residual into h_s ----
    {
      int pbase = 2 - half * 2;      // partner channels
#pragma unroll
      for (int i = 0; i < 3; ++i) {
        int tau = wave + 16 * i;
        int Mt = tau >> 3, Nt = tau & 7;
#pragma unroll
        for (int ss = 0; ss < 2; ++ss) {
          int s = pbase + ss;
          bf16x8 a = *(const bf16x8*)(afrag + (((Mt * 4 + s) * 64 + lane) << 3));
          bf16x8 bb = *(const bf16x8*)(wfL + ((Nt * 4 + s) * 512 + lane * 8));
          acc[i] = __builtin_amdgcn_mfma_f32_16x16x32_bf16(a, bb, acc[i], 0, 0, 0);
        }
      }
      const float* fb = full_b + layer * 128;
#pragma unroll
      for (int i = 0; i < 3; ++i) {
        int tau = wave + 16 * i;
        int Mt = tau >> 3, Nt = tau & 7;
        int col = Nt * 16 + l15;
        float bias = fb[col];
        int Rb = Mt * 16 + quad * 4;
#pragma unroll
        for (int r = 0; r < 4; ++r) {
          int R = Rb + r;
          if (R < 81) h_s[R * 128 + col] += fmaxf(acc[i][r] + bias, 0.f);
        }
      }
    }
    __syncthreads();
  }

  // ---- out = h @ out_w + out_b (half 0 writes) ----
  if (half == 0) {
    int row = tid >> 3, g8 = tid & 7;
    if (row < 81) {
      const float* hr = h_s + row * 128;
      float o0 = 0.f, o1 = 0.f, o2 = 0.f, o3 = 0.f;
#pragma unroll
      for (int it = 0; it < 4; ++it) {
        int cc = g8 * 4 + it * 32;
        float4 f = *(const float4*)(hr + cc);
        float4 wA = *(const float4*)(out_w + (cc + 0) * 4);
        float4 wB = *(const float4*)(out_w + (cc + 1) * 4);
        float4 wC = *(const float4*)(out_w + (cc + 2) * 4);
        float4 wD = *(const float4*)(out_w + (cc + 3) * 4);
        o0 += f.x * wA.x + f.y * wB.x + f.z * wC.x + f.w * wD.x;
        o1 += f.x * wA.y + f.y * wB.y + f.z * wC.y + f.w * wD.y;
        o2 += f.x * wA.z + f.y * wB.z + f.z * wC.z + f.w * wD.z;
        o3 += f.x * wA.w + f.y * wB.w + f.z * wC.w + f.w * wD.w;
      }
#pragma unroll
      for (int off = 1; off < 8; off <<= 1) {
        o0 += __shfl_xor(o0, off); o1 += __shfl_xor(o1, off);
        o2 += __shfl_xor(o2, off); o3 += __shfl_xor(o3, off);
      }
      if (g8 == 0) {
        *(float4*)(out + ((size_t)b * 81 + row) * 4) =
            make_float4(o0 + out_b[0], o1 + out_b[1], o2 + out_b[2], o3 + out_b[3]);
      }
    }
  }
}

extern "C" void kernel_launch(void* const* d_in, const int* in_sizes, int n_in,
                              void* d_out, int out_size, void* d_ws, size_t ws_size,
                              hipStream_t stream) {
  const float* x      = (const float*)d_in[0];
  const float* in_w   = (const float*)d_in[1];
  const float* in_b   = (const float*)d_in[2];
  const float* ln_g   = (const float*)d_in[3];
  const float* ln_b   = (const float*)d_in[4];
  const float* qkv_w  = (const float*)d_in[5];
  const float* qkv_b  = (const float*)d_in[6];
  const float* full_w = (const float*)d_in[7];
  const float* full_b = (const float*)d_in[8];
  const float* out_w  = (const float*)d_in[9];
  const float* out_b  = (const float*)d_in[10];

  bf* wq     = (bf*)d_ws;                  // 196608 bf16
  bf* wf     = wq + 196608;                // 65536 bf16
  bf* attg   = wf + 65536;                 // 128*2*81*64 = 1327104 bf16
  int* flags = (int*)(attg + 1327104);     // 256*4 ints (poisoned each launch)
  float* out = (float*)d_out;

  k_prep_w<<<128, 256, 0, stream>>>(qkv_w, full_w, wq, wf);
  k_net<<<256, 1024, 0, stream>>>(x, in_w, in_b, ln_g, ln_b, qkv_b, full_b,
                                  out_w, out_b, wq, wf, attg, flags, out);
}